// Round 4
// baseline (202.764 us; speedup 1.0000x reference)
//
#include <hip/hip_runtime.h>
#include <hip/hip_bf16.h>

#define ALPHA2 0.04f   // leaky(leaky(x)) slope for x<0: 0.2*0.2

typedef __attribute__((ext_vector_type(8))) short short8;
typedef __attribute__((ext_vector_type(4))) float floatx4;
typedef __attribute__((ext_vector_type(8))) unsigned short ushort8;

// ---- bf16 helpers (raw round-to-nearest-even; values are finite) ----
__device__ __forceinline__ unsigned short f2bf(float f) {
    unsigned u = __float_as_uint(f);
    unsigned r = (u + 0x7fffu + ((u >> 16) & 1u)) >> 16;
    return (unsigned short)r;
}
__device__ __forceinline__ float bf2f(unsigned short h) {
    return __uint_as_float((unsigned)h << 16);
}

// async 16B global->LDS (gfx950). LDS dest is wave-uniform base + lane*16.
__device__ __forceinline__ void async_copy16(const float* g, float* lds_base) {
    __builtin_amdgcn_global_load_lds(
        (const __attribute__((address_space(1))) unsigned int*)g,
        (__attribute__((address_space(3))) unsigned int*)lds_base, 16, 0, 0);
}

// NOTE on layout: Pb/Qb/Rb rows are stored with a fixed column permutation
//   c' = (c & 15)*8 + (c >> 4)   (c = canonical col, c' = stored col)
// chosen so each MFMA lane's 8 accumulator values are contiguous -> register-
// direct coalesced ushort8 stores. Aggregation is elementwise in col, so it
// works in permuted space and un-permutes only bias reads and out writes.

// ---------------- prep: W -> fragment-ordered bf16 Bfr + zero count ---------
__global__ void k_prep(const float* __restrict__ W, unsigned short* __restrict__ Bfr,
                       int* __restrict__ count, int NE) {
    int idx = blockIdx.x * blockDim.x + threadIdx.x;
    if (idx < 3 * 128 * 128) {
        int kk = idx & 7, n = (idx >> 3) & 127, g = idx >> 10;
        int slice = g >> 4, kc = (g >> 2) & 3, quad = g & 3;
        int k = kc * 32 + quad * 8 + kk;
        Bfr[idx] = f2bf(W[(size_t)(slice * 128 + k) * 128 + n]);
    }
    if (idx < NE) count[idx] = 0;
}

// ---------------- fused edge-degree count + MFMA GEMM -----------------------
// Count blocks FIRST (blockIdx < NBcnt): their random-atomic latency hides
// under the 1500+ gemm blocks dispatched after them (previously they trailed
// the gemm and added ~9us of exposed tail). Gemm blocks: 64-row tile, async
// swizzled fp32 A staging, one barrier, B fragments from L2-resident Bfr.
__global__ __launch_bounds__(256, 4) void k_gemm_all(
        const float* __restrict__ ent, const float* __restrict__ rel,
        const unsigned short* __restrict__ Bfr,
        unsigned short* __restrict__ Pb, unsigned short* __restrict__ Qb,
        unsigned short* __restrict__ Rb,
        float* __restrict__ s1, float* __restrict__ s3, float* __restrict__ s2,
        const float* __restrict__ avec, int NE, int NR, int NBcnt, int NBent,
        const int* __restrict__ hidx, int* __restrict__ count,
        int* __restrict__ rank, int E) {
    __shared__ __align__(16) float Ash[64 * 128];   // 32KB, swizzled chunks
    int tid = threadIdx.x;
    int b = blockIdx.x;

    if (b < NBcnt) {             // fused degree-count blocks (run first)
        int e = b * 256 + tid;
        if (e < E) rank[e] = atomicAdd(count + hidx[e], 1);
        return;
    }
    int gb = b - NBcnt;

    bool isEnt = gb < NBent;
    const float* In = isEnt ? ent : rel;
    int nrows = isEnt ? NE : NR;
    int rowbase = (isEnt ? gb : gb - NBent) * 64;

    int wave = tid >> 6, lane = tid & 63;

    // stage A: LDS[row][slot] = Global[grow][slot ^ (row&7)]  (slot = 16B chunk)
    #pragma unroll
    for (int i = 0; i < 8; ++i) {
        int r = wave * 16 + i * 2 + (lane >> 5);
        int grow = rowbase + r;
        if (grow > nrows - 1) grow = nrows - 1;   // clamp: garbage masked at store
        int c = (lane & 31) ^ (r & 7);
        async_copy16(In + (size_t)grow * 128 + c * 4,
                     Ash + (size_t)(wave * 16 + i * 2) * 128);
    }
    __syncthreads();

    int m16 = lane & 15, quad = lane >> 4;
    int rs = wave * 16;
    int R = rs + m16, sw = R & 7;
    const float4* rowp = (const float4*)(Ash + (size_t)R * 128);

    float av[8];
    #pragma unroll
    for (int j = 0; j < 8; ++j) av[j] = avec[j * 16 + m16];

    int nphase = isEnt ? 2 : 1;
    for (int ph = 0; ph < nphase; ++ph) {
        int slice; unsigned short* Out; float* svec;
        if (isEnt) { slice = ph ? 2 : 0; Out = ph ? Qb : Pb; svec = ph ? s3 : s1; }
        else       { slice = 1; Out = Rb; svec = s2; }

        floatx4 acc[8];
        #pragma unroll
        for (int j = 0; j < 8; ++j) acc[j] = (floatx4){0.f, 0.f, 0.f, 0.f};

        short8 bf0[8], bf1[8];
        auto loadB = [&](int kc, short8* dst) {
            const unsigned short* bb =
                Bfr + (size_t)((slice * 4 + kc) * 4 + quad) * 1024 + m16 * 8;
            #pragma unroll
            for (int j = 0; j < 8; ++j) dst[j] = *(const short8*)(bb + j * 128);
        };
        auto doMfma = [&](int kc, short8* bf) {
            int c0 = kc * 8 + quad * 2;
            float4 fa = rowp[c0 ^ sw];
            float4 fb = rowp[(c0 + 1) ^ sw];
            short8 af;
            af[0] = (short)f2bf(fa.x); af[1] = (short)f2bf(fa.y);
            af[2] = (short)f2bf(fa.z); af[3] = (short)f2bf(fa.w);
            af[4] = (short)f2bf(fb.x); af[5] = (short)f2bf(fb.y);
            af[6] = (short)f2bf(fb.z); af[7] = (short)f2bf(fb.w);
            #pragma unroll
            for (int j = 0; j < 8; ++j)
                acc[j] = __builtin_amdgcn_mfma_f32_16x16x32_bf16(af, bf[j], acc[j], 0, 0, 0);
        };
        loadB(0, bf0);
        loadB(1, bf1);
        doMfma(0, bf0);
        loadB(2, bf0);
        doMfma(1, bf1);
        loadB(3, bf1);
        doMfma(2, bf0);
        doMfma(3, bf1);

        // epilogue: register-direct permuted store + fused svec = row·avec
        #pragma unroll
        for (int reg = 0; reg < 4; ++reg) {
            int row = rowbase + rs + quad * 4 + reg;
            float part = 0.f;
            ushort8 v;
            #pragma unroll
            for (int j = 0; j < 8; ++j) {
                float x = acc[j][reg];
                part = fmaf(x, av[j], part);
                v[j] = f2bf(x);
            }
            #pragma unroll
            for (int off = 1; off < 16; off <<= 1) part += __shfl_xor(part, off);
            if (row < nrows) {
                *(ushort8*)(Out + (size_t)row * 128 + m16 * 8) = v;
                if (m16 == 0) svec[row] = part;
            }
        }
    }
}

// ---------------- hierarchical exclusive scan of count -> rowstart ----------
__device__ __forceinline__ int block_incl_scan256(int s, int* sh, int t) {
    sh[t] = s; __syncthreads();
    #pragma unroll
    for (int off = 1; off < 256; off <<= 1) {
        int x = 0;
        if (t >= off) x = sh[t - off];
        __syncthreads();
        sh[t] += x;
        __syncthreads();
    }
    return sh[t];
}

__global__ __launch_bounds__(256) void k_scan_a(const int* __restrict__ count, int NE,
                                                int* __restrict__ bsum) {
    __shared__ int sh[256];
    int b = blockIdx.x, t = threadIdx.x;
    int base = b * 1024 + t * 4, s = 0;
    #pragma unroll
    for (int j = 0; j < 4; ++j) { int i = base + j; if (i < NE) s += count[i]; }
    sh[t] = s; __syncthreads();
    for (int off = 128; off > 0; off >>= 1) {
        if (t < off) sh[t] += sh[t + off];
        __syncthreads();
    }
    if (t == 0) bsum[b] = sh[0];
}

// scan_c with the former scan_b inlined: every block scans the (<=256-entry)
// bsum array itself in LDS, then scans its own 1024 counters. NB=98 here.
__global__ __launch_bounds__(256) void k_scan_c(const int* __restrict__ count, int NE,
                                                const int* __restrict__ bsum, int NB,
                                                int* __restrict__ rowstart, int E) {
    __shared__ int sh[256];
    int b = blockIdx.x, t = threadIdx.x;
    int sb = (t < NB) ? bsum[t] : 0;
    (void)block_incl_scan256(sb, sh, t);        // sh now holds inclusive bsum scan
    int base0 = (b == 0) ? 0 : sh[b - 1];       // exclusive prefix for this block
    __syncthreads();                             // before reusing sh
    int base = b * 1024 + t * 4;
    int v[4]; int s = 0;
    #pragma unroll
    for (int j = 0; j < 4; ++j) { int i = base + j; v[j] = (i < NE) ? count[i] : 0; s += v[j]; }
    int incl = block_incl_scan256(s, sh, t);
    int excl = base0 + incl - s;
    #pragma unroll
    for (int j = 0; j < 4; ++j) {
        int i = base + j;
        if (i < NE) { rowstart[i] = excl; excl += v[j]; }
    }
    if (b == 0 && t == 0) rowstart[NE] = E;
}

// ---------------- edge pass 2: pure CSR permutation scatter -----------------
// Writes only the packed (r<<17)|t key (4B). Score/exp moved into aggregation
// where s2/s3 gathers amortize against the Qb/Rb row gathers. t < 2^17
// (NE=100k), r < 2^10 (NR=1000).
__global__ void k_scatter_rt(const int* __restrict__ h, const int* __restrict__ r,
                             const int* __restrict__ t,
                             const int* __restrict__ rowstart,
                             const int* __restrict__ rank,
                             unsigned* __restrict__ rt, int E) {
    int e = blockIdx.x * blockDim.x + threadIdx.x;
    if (e >= E) return;
    rt[rowstart[h[e]] + rank[e]] = ((unsigned)r[e] << 17) | (unsigned)t[e];
}

// ---------------- per-entity aggregation: 16 lanes per entity ---------------
// Computes ev = exp(leaky2(s1[n]+s2[r]+s3[t]+a_b)) inline (same fp32 ops and
// CSR order as before -> bitwise-identical numerics). 4x unrolled edge loop
// -> 8 row gathers + 8 scalar gathers in flight per 16-lane group.
__global__ __launch_bounds__(256) void k_aggregate(const int* __restrict__ rowstart,
                                                   const unsigned* __restrict__ rt,
                                                   const unsigned short* __restrict__ Pb,
                                                   const unsigned short* __restrict__ Qb,
                                                   const unsigned short* __restrict__ Rb,
                                                   const float* __restrict__ s1,
                                                   const float* __restrict__ s2,
                                                   const float* __restrict__ s3,
                                                   const float* __restrict__ a_b,
                                                   const float* __restrict__ bias,
                                                   float* __restrict__ out, int NE) {
    int gid = blockIdx.x * blockDim.x + threadIdx.x;
    int n = gid >> 4;        // entity
    int sl = gid & 15;       // sublane: covers permuted cols sl*8..sl*8+7
    if (n >= NE) return;
    int start = rowstart[n], end = rowstart[n + 1];
    int c0 = sl * 8;
    float base = s1[n] + a_b[0];
    float acc[8] = {};
    float evsum = 0.f;
    int i = start;
    for (; i + 4 <= end; i += 4) {
        unsigned u0 = rt[i], u1 = rt[i + 1], u2 = rt[i + 2], u3 = rt[i + 3];
        unsigned t0 = u0 & 0x1FFFFu, r0i = u0 >> 17;
        unsigned t1 = u1 & 0x1FFFFu, r1i = u1 >> 17;
        unsigned t2 = u2 & 0x1FFFFu, r2i = u2 >> 17;
        unsigned t3 = u3 & 0x1FFFFu, r3i = u3 >> 17;
        ushort8 q0 = *(const ushort8*)(Qb + (size_t)t0 * 128 + c0);
        ushort8 rr0 = *(const ushort8*)(Rb + (size_t)r0i * 128 + c0);
        ushort8 q1 = *(const ushort8*)(Qb + (size_t)t1 * 128 + c0);
        ushort8 rr1 = *(const ushort8*)(Rb + (size_t)r1i * 128 + c0);
        ushort8 q2 = *(const ushort8*)(Qb + (size_t)t2 * 128 + c0);
        ushort8 rr2 = *(const ushort8*)(Rb + (size_t)r2i * 128 + c0);
        ushort8 q3 = *(const ushort8*)(Qb + (size_t)t3 * 128 + c0);
        ushort8 rr3 = *(const ushort8*)(Rb + (size_t)r3i * 128 + c0);
        float x0 = base + s2[r0i] + s3[t0];
        float x1 = base + s2[r1i] + s3[t1];
        float x2 = base + s2[r2i] + s3[t2];
        float x3 = base + s2[r3i] + s3[t3];
        x0 = (x0 >= 0.f) ? x0 : ALPHA2 * x0;
        x1 = (x1 >= 0.f) ? x1 : ALPHA2 * x1;
        x2 = (x2 >= 0.f) ? x2 : ALPHA2 * x2;
        x3 = (x3 >= 0.f) ? x3 : ALPHA2 * x3;
        float ev0 = __expf(x0), ev1 = __expf(x1);
        float ev2 = __expf(x2), ev3 = __expf(x3);
        evsum += (ev0 + ev1) + (ev2 + ev3);
        #pragma unroll
        for (int j = 0; j < 8; ++j) {
            acc[j] = fmaf(ev0, bf2f(q0[j]) + bf2f(rr0[j]), acc[j]);
            acc[j] = fmaf(ev1, bf2f(q1[j]) + bf2f(rr1[j]), acc[j]);
            acc[j] = fmaf(ev2, bf2f(q2[j]) + bf2f(rr2[j]), acc[j]);
            acc[j] = fmaf(ev3, bf2f(q3[j]) + bf2f(rr3[j]), acc[j]);
        }
    }
    for (; i < end; ++i) {
        unsigned u0 = rt[i];
        unsigned t0 = u0 & 0x1FFFFu, r0i = u0 >> 17;
        ushort8 q0 = *(const ushort8*)(Qb + (size_t)t0 * 128 + c0);
        ushort8 rr0 = *(const ushort8*)(Rb + (size_t)r0i * 128 + c0);
        float x0 = base + s2[r0i] + s3[t0];
        x0 = (x0 >= 0.f) ? x0 : ALPHA2 * x0;
        float ev0 = __expf(x0);
        evsum += ev0;
        #pragma unroll
        for (int j = 0; j < 8; ++j)
            acc[j] = fmaf(ev0, bf2f(q0[j]) + bf2f(rr0[j]), acc[j]);
    }
    // inverse permutation: stored col sl*8+j  <->  canonical col j*16+sl
    float bi[8];
    #pragma unroll
    for (int j = 0; j < 8; ++j) bi[j] = bias[j * 16 + sl];
    float o[8];
    if (end > start) {
        float inv = 1.f / evsum;
        ushort8 pb = *(const ushort8*)(Pb + (size_t)n * 128 + c0);
        #pragma unroll
        for (int j = 0; j < 8; ++j) o[j] = bf2f(pb[j]) + acc[j] * inv + bi[j];
    } else {
        #pragma unroll
        for (int j = 0; j < 8; ++j) o[j] = bi[j];
    }
    #pragma unroll
    for (int j = 0; j < 8; ++j)
        out[(size_t)n * 128 + j * 16 + sl] = fmaxf(o[j], 0.f);
}

// ============================================================================
static inline size_t align_up(size_t x, size_t a) { return (x + a - 1) / a * a; }

extern "C" void kernel_launch(void* const* d_in, const int* in_sizes, int n_in,
                              void* d_out, int out_size, void* d_ws, size_t ws_size,
                              hipStream_t stream) {
    const int* h_index = (const int*)d_in[0];
    const int* r_index = (const int*)d_in[1];
    const int* t_index = (const int*)d_in[2];
    const float* ent = (const float*)d_in[3];
    const float* rel = (const float*)d_in[4];
    const float* W = (const float*)d_in[5];
    const float* a = (const float*)d_in[6];
    const float* a_b = (const float*)d_in[7];
    const float* bias = (const float*)d_in[8];
    float* out = (float*)d_out;

    int E = in_sizes[0];
    int NE = in_sizes[3] / 128;
    int NR = in_sizes[4] / 128;

    char* p = (char*)d_ws;
    auto alloc = [&](size_t bytes) { char* q = p; p += align_up(bytes, 256); return (void*)q; };
    unsigned short* Pb = (unsigned short*)alloc((size_t)NE * 128 * 2);
    unsigned short* Qb = (unsigned short*)alloc((size_t)NE * 128 * 2);
    unsigned short* Rb = (unsigned short*)alloc((size_t)NR * 128 * 2);
    unsigned short* Bfr = (unsigned short*)alloc((size_t)3 * 128 * 128 * 2);
    float* s1 = (float*)alloc((size_t)NE * 4);
    float* s3 = (float*)alloc((size_t)NE * 4);
    float* s2 = (float*)alloc((size_t)NR * 4);
    int* count = (int*)alloc((size_t)NE * 4);
    int* rowstart = (int*)alloc((size_t)(NE + 1) * 4);
    int* rank = (int*)alloc((size_t)E * 4);
    int NB = (NE + 1023) / 1024;
    int* bsum = (int*)alloc((size_t)NB * 4);
    unsigned* rt = (unsigned*)alloc((size_t)E * 4);
    (void)ws_size; (void)n_in; (void)out_size;

    // 1. prep: W -> fragment-ordered bf16 + zero counters (before fused count!)
    int nprep = (NE > 3 * 128 * 128) ? NE : 3 * 128 * 128;
    k_prep<<<(nprep + 255) / 256, 256, 0, stream>>>(W, Bfr, count, NE);
    // 2. edge-degree count (FIRST) + three GEMMs in ONE dispatch
    int NBent = (NE + 63) / 64, NBrel = (NR + 63) / 64;
    int NBcnt = (E + 255) / 256;
    k_gemm_all<<<NBcnt + NBent + NBrel, 256, 0, stream>>>(
        ent, rel, Bfr, Pb, Qb, Rb, s1, s3, s2, a, NE, NR, NBcnt, NBent,
        h_index, count, rank, E);
    // 3-4. scan -> rowstart (scan_b folded into scan_c: NB=98 <= 256)
    k_scan_a<<<NB, 256, 0, stream>>>(count, NE, bsum);
    k_scan_c<<<NB, 256, 0, stream>>>(count, NE, bsum, NB, rowstart, E);
    // 5. edge pass 2: pure CSR permutation scatter (4B keys, no score work)
    k_scatter_rt<<<(E + 255) / 256, 256, 0, stream>>>(h_index, r_index, t_index,
                                                      rowstart, rank, rt, E);
    // 6. aggregate + inline score/exp + bias + relu (16 lanes/entity)
    k_aggregate<<<(NE * 16 + 255) / 256, 256, 0, stream>>>(rowstart, rt, Pb, Qb, Rb,
                                                           s1, s2, s3, a_b, bias,
                                                           out, NE);
}

// Round 5
// 190.537 us; speedup vs baseline: 1.0642x; 1.0642x over previous
//
#include <hip/hip_runtime.h>
#include <hip/hip_bf16.h>

#define ALPHA2 0.04f   // leaky(leaky(x)) slope for x<0: 0.2*0.2

typedef __attribute__((ext_vector_type(8))) short short8;
typedef __attribute__((ext_vector_type(4))) float floatx4;
typedef __attribute__((ext_vector_type(8))) unsigned short ushort8;

// ---- bf16 helpers (raw round-to-nearest-even; values are finite) ----
__device__ __forceinline__ unsigned short f2bf(float f) {
    unsigned u = __float_as_uint(f);
    unsigned r = (u + 0x7fffu + ((u >> 16) & 1u)) >> 16;
    return (unsigned short)r;
}
__device__ __forceinline__ float bf2f(unsigned short h) {
    return __uint_as_float((unsigned)h << 16);
}

// async 16B global->LDS (gfx950). LDS dest is wave-uniform base + lane*16.
__device__ __forceinline__ void async_copy16(const float* g, float* lds_base) {
    __builtin_amdgcn_global_load_lds(
        (const __attribute__((address_space(1))) unsigned int*)g,
        (__attribute__((address_space(3))) unsigned int*)lds_base, 16, 0, 0);
}

// NOTE on layout: Pb/Qb/Rb rows are stored with a fixed column permutation
//   c' = (c & 15)*8 + (c >> 4)   (c = canonical col, c' = stored col)
// chosen so each MFMA lane's 8 accumulator values are contiguous -> register-
// direct coalesced ushort8 stores. Aggregation is elementwise in col, so it
// works in permuted space and un-permutes only bias reads and out writes.

// ---------------- prep: W -> fragment-ordered bf16 Bfr + zero count/flags ---
__global__ void k_prep(const float* __restrict__ W, unsigned short* __restrict__ Bfr,
                       int* __restrict__ count, int NE,
                       unsigned long long* __restrict__ tstate, int NBt) {
    int idx = blockIdx.x * blockDim.x + threadIdx.x;
    if (idx < 3 * 128 * 128) {
        int kk = idx & 7, n = (idx >> 3) & 127, g = idx >> 10;
        int slice = g >> 4, kc = (g >> 2) & 3, quad = g & 3;
        int k = kc * 32 + quad * 8 + kk;
        Bfr[idx] = f2bf(W[(size_t)(slice * 128 + k) * 128 + n]);
    }
    if (idx < NE) count[idx] = 0;
    if (idx < NBt) tstate[idx] = 0ull;
}

// ---------------- fused MFMA GEMM + INTERLEAVED edge-degree count -----------
// Count blocks are spread proportionally through the dispatch (b*NBcnt/total
// mapping): their random-atomic latency hides in gemm blocks' idle wave slots
// instead of forming a serial prefix/suffix phase (r1/r4 lesson: block ORDER
// does not overlap; only per-CU mixing does). Each count block grid-strides
// 1024 edges. Gemm blocks: 64-row tile, async swizzled fp32 A staging, one
// barrier, B fragments from L2-resident Bfr (structure proven since r1).
__global__ __launch_bounds__(256, 4) void k_gemm_all(
        const float* __restrict__ ent, const float* __restrict__ rel,
        const unsigned short* __restrict__ Bfr,
        unsigned short* __restrict__ Pb, unsigned short* __restrict__ Qb,
        unsigned short* __restrict__ Rb,
        float* __restrict__ s1, float* __restrict__ s3, float* __restrict__ s2,
        const float* __restrict__ avec, int NE, int NR, int NBcnt, int NBent,
        int total,
        const int* __restrict__ hidx, int* __restrict__ count,
        int* __restrict__ rank, int E) {
    __shared__ __align__(16) float Ash[64 * 128];   // 32KB, swizzled chunks
    int tid = threadIdx.x;
    int b = blockIdx.x;

    // proportional interleave: count block iff floor((b+1)*NBcnt/total) bumps
    int cb_before = (int)(((long long)b * NBcnt) / total);
    int cb_after = (int)(((long long)(b + 1) * NBcnt) / total);
    if (cb_after > cb_before) {          // count block, index cb_before
        int base_e = cb_before * 1024;
        #pragma unroll
        for (int k2 = 0; k2 < 4; ++k2) {
            int e = base_e + k2 * 256 + tid;
            if (e < E) rank[e] = atomicAdd(count + hidx[e], 1);
        }
        return;
    }
    int gb = b - cb_after;               // gemm block index 0..NBgemm-1

    bool isEnt = gb < NBent;
    const float* In = isEnt ? ent : rel;
    int nrows = isEnt ? NE : NR;
    int rowbase = (isEnt ? gb : gb - NBent) * 64;

    int wave = tid >> 6, lane = tid & 63;

    // stage A: LDS[row][slot] = Global[grow][slot ^ (row&7)]  (slot = 16B chunk)
    #pragma unroll
    for (int i = 0; i < 8; ++i) {
        int r = wave * 16 + i * 2 + (lane >> 5);
        int grow = rowbase + r;
        if (grow > nrows - 1) grow = nrows - 1;   // clamp: garbage masked at store
        int c = (lane & 31) ^ (r & 7);
        async_copy16(In + (size_t)grow * 128 + c * 4,
                     Ash + (size_t)(wave * 16 + i * 2) * 128);
    }
    __syncthreads();

    int m16 = lane & 15, quad = lane >> 4;
    int rs = wave * 16;
    int R = rs + m16, sw = R & 7;
    const float4* rowp = (const float4*)(Ash + (size_t)R * 128);

    float av[8];
    #pragma unroll
    for (int j = 0; j < 8; ++j) av[j] = avec[j * 16 + m16];

    int nphase = isEnt ? 2 : 1;
    for (int ph = 0; ph < nphase; ++ph) {
        int slice; unsigned short* Out; float* svec;
        if (isEnt) { slice = ph ? 2 : 0; Out = ph ? Qb : Pb; svec = ph ? s3 : s1; }
        else       { slice = 1; Out = Rb; svec = s2; }

        floatx4 acc[8];
        #pragma unroll
        for (int j = 0; j < 8; ++j) acc[j] = (floatx4){0.f, 0.f, 0.f, 0.f};

        short8 bf0[8], bf1[8];
        auto loadB = [&](int kc, short8* dst) {
            const unsigned short* bb =
                Bfr + (size_t)((slice * 4 + kc) * 4 + quad) * 1024 + m16 * 8;
            #pragma unroll
            for (int j = 0; j < 8; ++j) dst[j] = *(const short8*)(bb + j * 128);
        };
        auto doMfma = [&](int kc, short8* bf) {
            int c0 = kc * 8 + quad * 2;
            float4 fa = rowp[c0 ^ sw];
            float4 fb = rowp[(c0 + 1) ^ sw];
            short8 af;
            af[0] = (short)f2bf(fa.x); af[1] = (short)f2bf(fa.y);
            af[2] = (short)f2bf(fa.z); af[3] = (short)f2bf(fa.w);
            af[4] = (short)f2bf(fb.x); af[5] = (short)f2bf(fb.y);
            af[6] = (short)f2bf(fb.z); af[7] = (short)f2bf(fb.w);
            #pragma unroll
            for (int j = 0; j < 8; ++j)
                acc[j] = __builtin_amdgcn_mfma_f32_16x16x32_bf16(af, bf[j], acc[j], 0, 0, 0);
        };
        loadB(0, bf0);
        loadB(1, bf1);
        doMfma(0, bf0);
        loadB(2, bf0);
        doMfma(1, bf1);
        loadB(3, bf1);
        doMfma(2, bf0);
        doMfma(3, bf1);

        // epilogue: register-direct permuted store + fused svec = row·avec
        #pragma unroll
        for (int reg = 0; reg < 4; ++reg) {
            int row = rowbase + rs + quad * 4 + reg;
            float part = 0.f;
            ushort8 v;
            #pragma unroll
            for (int j = 0; j < 8; ++j) {
                float x = acc[j][reg];
                part = fmaf(x, av[j], part);
                v[j] = f2bf(x);
            }
            #pragma unroll
            for (int off = 1; off < 16; off <<= 1) part += __shfl_xor(part, off);
            if (row < nrows) {
                *(ushort8*)(Out + (size_t)row * 128 + m16 * 8) = v;
                if (m16 == 0) svec[row] = part;
            }
        }
    }
}

// ---------------- single-pass scan: count -> rowstart (decoupled lookback) --
// NB (<=256) blocks, ALL co-resident (NB <= #CUs) so polling cannot deadlock.
// Each block publishes its tile sum (flag|sum packed in 8B), then thread t
// polls predecessor t's partial (wave-parallel lookback -> no serial chain),
// block-reduces to the exclusive base, and writes its 1024 rowstart entries.
__device__ __forceinline__ int block_incl_scan256(int s, int* sh, int t) {
    sh[t] = s; __syncthreads();
    #pragma unroll
    for (int off = 1; off < 256; off <<= 1) {
        int x = 0;
        if (t >= off) x = sh[t - off];
        __syncthreads();
        sh[t] += x;
        __syncthreads();
    }
    return sh[t];
}

__global__ __launch_bounds__(256) void k_scan1(const int* __restrict__ count, int NE,
                                               unsigned long long* __restrict__ tstate,
                                               int* __restrict__ rowstart, int E) {
    __shared__ int sh[256];
    int b = blockIdx.x, t = threadIdx.x;
    int base = b * 1024 + t * 4;
    int v[4]; int s = 0;
    #pragma unroll
    for (int j = 0; j < 4; ++j) { int i = base + j; v[j] = (i < NE) ? count[i] : 0; s += v[j]; }
    int incl = block_incl_scan256(s, sh, t);
    if (t == 0) {
        unsigned long long pk = (1ull << 32) | (unsigned)sh[255];
        __hip_atomic_store(&tstate[b], pk, __ATOMIC_RELEASE, __HIP_MEMORY_SCOPE_AGENT);
    }
    int myval = 0;
    if (t < b) {                        // b <= 255, one predecessor per thread
        unsigned long long pk;
        for (;;) {
            pk = __hip_atomic_load(&tstate[t], __ATOMIC_ACQUIRE, __HIP_MEMORY_SCOPE_AGENT);
            if (pk >> 32) break;
            __builtin_amdgcn_s_sleep(1);
        }
        myval = (int)(unsigned)pk;
    }
    __syncthreads();                    // sh reuse boundary
    sh[t] = myval; __syncthreads();
    for (int off = 128; off > 0; off >>= 1) {
        if (t < off) sh[t] += sh[t + off];
        __syncthreads();
    }
    int excl = sh[0] + incl - s;
    #pragma unroll
    for (int j = 0; j < 4; ++j) {
        int i = base + j;
        if (i < NE) { rowstart[i] = excl; excl += v[j]; }
    }
    if (b == 0 && t == 0) rowstart[NE] = E;
}

// ---------------- edge pass 2: pure CSR permutation scatter -----------------
// Writes only the packed (r<<17)|t key (4B). t < 2^17 (NE=100k), r < 2^10.
__global__ void k_scatter_rt(const int* __restrict__ h, const int* __restrict__ r,
                             const int* __restrict__ t,
                             const int* __restrict__ rowstart,
                             const int* __restrict__ rank,
                             unsigned* __restrict__ rt, int E) {
    int e = blockIdx.x * blockDim.x + threadIdx.x;
    if (e >= E) return;
    rt[rowstart[h[e]] + rank[e]] = ((unsigned)r[e] << 17) | (unsigned)t[e];
}

// ---------------- per-entity aggregation: 16 lanes per entity ---------------
// Computes ev = exp(leaky2(s1[n]+s2[r]+s3[t]+a_b)) inline (same fp32 ops and
// CSR order as the reference path). 4x unrolled edge loop -> 8 row gathers +
// 8 scalar gathers in flight per 16-lane group.
__global__ __launch_bounds__(256) void k_aggregate(const int* __restrict__ rowstart,
                                                   const unsigned* __restrict__ rt,
                                                   const unsigned short* __restrict__ Pb,
                                                   const unsigned short* __restrict__ Qb,
                                                   const unsigned short* __restrict__ Rb,
                                                   const float* __restrict__ s1,
                                                   const float* __restrict__ s2,
                                                   const float* __restrict__ s3,
                                                   const float* __restrict__ a_b,
                                                   const float* __restrict__ bias,
                                                   float* __restrict__ out, int NE) {
    int gid = blockIdx.x * blockDim.x + threadIdx.x;
    int n = gid >> 4;        // entity
    int sl = gid & 15;       // sublane: covers permuted cols sl*8..sl*8+7
    if (n >= NE) return;
    int start = rowstart[n], end = rowstart[n + 1];
    int c0 = sl * 8;
    float base = s1[n] + a_b[0];
    float acc[8] = {};
    float evsum = 0.f;
    int i = start;
    for (; i + 4 <= end; i += 4) {
        unsigned u0 = rt[i], u1 = rt[i + 1], u2 = rt[i + 2], u3 = rt[i + 3];
        unsigned t0 = u0 & 0x1FFFFu, r0i = u0 >> 17;
        unsigned t1 = u1 & 0x1FFFFu, r1i = u1 >> 17;
        unsigned t2 = u2 & 0x1FFFFu, r2i = u2 >> 17;
        unsigned t3 = u3 & 0x1FFFFu, r3i = u3 >> 17;
        ushort8 q0 = *(const ushort8*)(Qb + (size_t)t0 * 128 + c0);
        ushort8 rr0 = *(const ushort8*)(Rb + (size_t)r0i * 128 + c0);
        ushort8 q1 = *(const ushort8*)(Qb + (size_t)t1 * 128 + c0);
        ushort8 rr1 = *(const ushort8*)(Rb + (size_t)r1i * 128 + c0);
        ushort8 q2 = *(const ushort8*)(Qb + (size_t)t2 * 128 + c0);
        ushort8 rr2 = *(const ushort8*)(Rb + (size_t)r2i * 128 + c0);
        ushort8 q3 = *(const ushort8*)(Qb + (size_t)t3 * 128 + c0);
        ushort8 rr3 = *(const ushort8*)(Rb + (size_t)r3i * 128 + c0);
        float x0 = base + s2[r0i] + s3[t0];
        float x1 = base + s2[r1i] + s3[t1];
        float x2 = base + s2[r2i] + s3[t2];
        float x3 = base + s2[r3i] + s3[t3];
        x0 = (x0 >= 0.f) ? x0 : ALPHA2 * x0;
        x1 = (x1 >= 0.f) ? x1 : ALPHA2 * x1;
        x2 = (x2 >= 0.f) ? x2 : ALPHA2 * x2;
        x3 = (x3 >= 0.f) ? x3 : ALPHA2 * x3;
        float ev0 = __expf(x0), ev1 = __expf(x1);
        float ev2 = __expf(x2), ev3 = __expf(x3);
        evsum += (ev0 + ev1) + (ev2 + ev3);
        #pragma unroll
        for (int j = 0; j < 8; ++j) {
            acc[j] = fmaf(ev0, bf2f(q0[j]) + bf2f(rr0[j]), acc[j]);
            acc[j] = fmaf(ev1, bf2f(q1[j]) + bf2f(rr1[j]), acc[j]);
            acc[j] = fmaf(ev2, bf2f(q2[j]) + bf2f(rr2[j]), acc[j]);
            acc[j] = fmaf(ev3, bf2f(q3[j]) + bf2f(rr3[j]), acc[j]);
        }
    }
    for (; i < end; ++i) {
        unsigned u0 = rt[i];
        unsigned t0 = u0 & 0x1FFFFu, r0i = u0 >> 17;
        ushort8 q0 = *(const ushort8*)(Qb + (size_t)t0 * 128 + c0);
        ushort8 rr0 = *(const ushort8*)(Rb + (size_t)r0i * 128 + c0);
        float x0 = base + s2[r0i] + s3[t0];
        x0 = (x0 >= 0.f) ? x0 : ALPHA2 * x0;
        float ev0 = __expf(x0);
        evsum += ev0;
        #pragma unroll
        for (int j = 0; j < 8; ++j)
            acc[j] = fmaf(ev0, bf2f(q0[j]) + bf2f(rr0[j]), acc[j]);
    }
    // inverse permutation: stored col sl*8+j  <->  canonical col j*16+sl
    float bi[8];
    #pragma unroll
    for (int j = 0; j < 8; ++j) bi[j] = bias[j * 16 + sl];
    float o[8];
    if (end > start) {
        float inv = 1.f / evsum;
        ushort8 pb = *(const ushort8*)(Pb + (size_t)n * 128 + c0);
        #pragma unroll
        for (int j = 0; j < 8; ++j) o[j] = bf2f(pb[j]) + acc[j] * inv + bi[j];
    } else {
        #pragma unroll
        for (int j = 0; j < 8; ++j) o[j] = bi[j];
    }
    #pragma unroll
    for (int j = 0; j < 8; ++j)
        out[(size_t)n * 128 + j * 16 + sl] = fmaxf(o[j], 0.f);
}

// ============================================================================
static inline size_t align_up(size_t x, size_t a) { return (x + a - 1) / a * a; }

extern "C" void kernel_launch(void* const* d_in, const int* in_sizes, int n_in,
                              void* d_out, int out_size, void* d_ws, size_t ws_size,
                              hipStream_t stream) {
    const int* h_index = (const int*)d_in[0];
    const int* r_index = (const int*)d_in[1];
    const int* t_index = (const int*)d_in[2];
    const float* ent = (const float*)d_in[3];
    const float* rel = (const float*)d_in[4];
    const float* W = (const float*)d_in[5];
    const float* a = (const float*)d_in[6];
    const float* a_b = (const float*)d_in[7];
    const float* bias = (const float*)d_in[8];
    float* out = (float*)d_out;

    int E = in_sizes[0];
    int NE = in_sizes[3] / 128;
    int NR = in_sizes[4] / 128;

    char* p = (char*)d_ws;
    auto alloc = [&](size_t bytes) { char* q = p; p += align_up(bytes, 256); return (void*)q; };
    unsigned short* Pb = (unsigned short*)alloc((size_t)NE * 128 * 2);
    unsigned short* Qb = (unsigned short*)alloc((size_t)NE * 128 * 2);
    unsigned short* Rb = (unsigned short*)alloc((size_t)NR * 128 * 2);
    unsigned short* Bfr = (unsigned short*)alloc((size_t)3 * 128 * 128 * 2);
    float* s1 = (float*)alloc((size_t)NE * 4);
    float* s3 = (float*)alloc((size_t)NE * 4);
    float* s2 = (float*)alloc((size_t)NR * 4);
    int* count = (int*)alloc((size_t)NE * 4);
    int* rowstart = (int*)alloc((size_t)(NE + 1) * 4);
    int* rank = (int*)alloc((size_t)E * 4);
    int NB = (NE + 1023) / 1024;                  // 98 tiles; must be <= 256
    unsigned long long* tstate = (unsigned long long*)alloc((size_t)NB * 8);
    unsigned* rt = (unsigned*)alloc((size_t)E * 4);
    (void)ws_size; (void)n_in; (void)out_size;

    // 1. prep: W -> fragment-ordered bf16 + zero count + zero lookback flags
    int nprep = (NE > 3 * 128 * 128) ? NE : 3 * 128 * 128;
    k_prep<<<(nprep + 255) / 256, 256, 0, stream>>>(W, Bfr, count, NE, tstate, NB);
    // 2. three GEMMs + INTERLEAVED degree-count blocks, ONE dispatch
    int NBent = (NE + 63) / 64, NBrel = (NR + 63) / 64;
    int NBgemm = NBent + NBrel;
    int NBcnt = (E + 1023) / 1024;
    int total = NBcnt + NBgemm;
    k_gemm_all<<<total, 256, 0, stream>>>(
        ent, rel, Bfr, Pb, Qb, Rb, s1, s3, s2, a, NE, NR, NBcnt, NBent, total,
        h_index, count, rank, E);
    // 3. single-pass scan -> rowstart (decoupled lookback, all blocks resident)
    k_scan1<<<NB, 256, 0, stream>>>(count, NE, tstate, rowstart, E);
    // 4. edge pass 2: pure CSR permutation scatter (4B keys)
    k_scatter_rt<<<(E + 255) / 256, 256, 0, stream>>>(h_index, r_index, t_index,
                                                      rowstart, rank, rt, E);
    // 5. aggregate + inline score/exp + bias + relu (16 lanes/entity)
    k_aggregate<<<(NE * 16 + 255) / 256, 256, 0, stream>>>(rowstart, rt, Pb, Qb, Rb,
                                                           s1, s2, s3, a_b, bias,
                                                           out, NE);
}